// Round 1
// baseline (502.564 us; speedup 1.0000x reference)
//
#include <hip/hip_runtime.h>
#include <cstdint>
#include <cstddef>

#define N_NODES 50000
#define N_EDGES 800000
#define D 64
#define CAP 64
#define MSG_EPS 1e-7f
#define LN_EPS 1e-5f

typedef __attribute__((ext_vector_type(8))) short short8;
typedef __attribute__((ext_vector_type(4))) float floatx4;

__device__ __forceinline__ unsigned short f2bf(float f) {
  unsigned u = __float_as_uint(f);
  u += 0x7FFFu + ((u >> 16) & 1u);
  return (unsigned short)(u >> 16);
}

// ---------------- K1: bucket edges by dst ----------------
__global__ __launch_bounds__(256) void k_scatter(const int* __restrict__ ei,
                                                 int* __restrict__ cnt,
                                                 int* __restrict__ slots) {
  int e = blockIdx.x * blockDim.x + threadIdx.x;
  if (e < N_EDGES) {
    int d = ei[N_EDGES + e];  // dst row of edge_index
    int pos = atomicAdd(&cnt[d], 1);
    if (pos < CAP) slots[d * CAP + pos] = e;
  }
}

// ---------------- K2: per-node online-softmax aggregation ----------------
// one wave per node, lane = channel; channels are independent -> no cross-lane ops
__global__ __launch_bounds__(256) void k_agg(const float* __restrict__ x,
                                             const int* __restrict__ ei,
                                             const float* __restrict__ ea,
                                             const int* __restrict__ cnt,
                                             const int* __restrict__ slots,
                                             float* __restrict__ aggout) {
  int w = (blockIdx.x * blockDim.x + threadIdx.x) >> 6;  // node id
  int l = threadIdx.x & 63;                              // channel
  if (w >= N_NODES) return;
  int deg = cnt[w];
  deg = deg > CAP ? CAP : deg;
  const int* sl = slots + w * CAP;
  float m = 0.f, dsum = 0.f, nsum = 0.f;  // msg >= eps > 0, so m=0 init is safe
  for (int k = 0; k < deg; ++k) {
    int e = sl[k];        // wave-uniform
    int s = ei[e];        // src, wave-uniform
    float v = ea[(size_t)e * D + l] + x[(size_t)s * D + l];
    v = fmaxf(v, 0.f) + MSG_EPS;
    float nm = fmaxf(m, v);
    float sc = __expf(m - nm);
    float ev = __expf(v - nm);
    dsum = dsum * sc + ev;
    nsum = nsum * sc + ev * v;
    m = nm;
  }
  float agg = (deg > 0) ? (nsum / dsum) : 0.f;
  aggout[(size_t)w * D + l] = agg + x[(size_t)w * D + l];
}

// ---------------- K3: fused MLP (GEMM1 + LN + ReLU + GEMM2), bf16 MFMA ----------------
#define W1P 72    // 64 + 8 pad (bf16 elems) -> 2-way banks, 16B-aligned frag rows
#define W2P 136   // 128 + 8 pad
#define PP 136

__global__ __launch_bounds__(256) void k_mlp(const float* __restrict__ o,
                                             const float* __restrict__ W1,
                                             const float* __restrict__ b1,
                                             const float* __restrict__ g1,
                                             const float* __restrict__ be1,
                                             const float* __restrict__ W2,
                                             const float* __restrict__ b2,
                                             float* __restrict__ out) {
  __shared__ unsigned short sW1[128 * W1P];
  __shared__ unsigned short sW2[64 * W2P];
  __shared__ unsigned short sP[4][16 * PP];
  int t = threadIdx.x;
  // stage weights as bf16 into LDS (once per block)
  for (int i = t; i < 128 * 64; i += 256) {
    int n = i >> 6, k = i & 63;
    sW1[n * W1P + k] = f2bf(W1[i]);
  }
  for (int i = t; i < 64 * 128; i += 256) {
    int n = i >> 7, k = i & 127;
    sW2[n * W2P + k] = f2bf(W2[i]);
  }
  __syncthreads();

  int w = t >> 6, l = t & 63;
  int lo = l & 15, q = l >> 4;  // col-in-tile, quad
  unsigned short* sPw = sP[w];

  float b1r[8], gr[8], ber[8];
  for (int f = 0; f < 8; ++f) {
    b1r[f] = b1[f * 16 + lo];
    gr[f]  = g1[f * 16 + lo];
    ber[f] = be1[f * 16 + lo];
  }
  float b2r[4];
  for (int f = 0; f < 4; ++f) b2r[f] = b2[f * 16 + lo];

  const int n_waves = 196 * 4;
  int wave_global = blockIdx.x * 4 + w;
  for (int tile = wave_global; tile < N_NODES / 16; tile += n_waves) {
    // A1 frags: A[m = lane&15][k = quad*8 + j + 32*kt]
    short8 a1[2];
    const float* arow = o + (size_t)(tile * 16 + lo) * D + q * 8;
    for (int kt = 0; kt < 2; ++kt) {
      const float4* p = reinterpret_cast<const float4*>(arow + kt * 32);
      float4 u = p[0], v2 = p[1];
      short8 r;
      r[0] = f2bf(u.x);  r[1] = f2bf(u.y);  r[2] = f2bf(u.z);  r[3] = f2bf(u.w);
      r[4] = f2bf(v2.x); r[5] = f2bf(v2.y); r[6] = f2bf(v2.z); r[7] = f2bf(v2.w);
      a1[kt] = r;
    }
    // GEMM1: h[16x128] = A1[16x64] @ W1^T ; B[k][n]=W1[n][k]
    floatx4 acc[8];
    for (int f = 0; f < 8; ++f) {
      floatx4 c = {0.f, 0.f, 0.f, 0.f};
      for (int kt = 0; kt < 2; ++kt) {
        const short8* bp = reinterpret_cast<const short8*>(
            &sW1[(f * 16 + lo) * W1P + q * 8 + kt * 32]);
        c = __builtin_amdgcn_mfma_f32_16x16x32_bf16(a1[kt], *bp, c, 0, 0, 0);
      }
      acc[f] = c;
    }
    // bias + LN + ReLU in C/D layout (row=(q*4+r), col=f*16+lo), write P to LDS
    asm volatile("s_waitcnt lgkmcnt(0)" ::: "memory");  // prev-iter a2 reads done
    for (int r = 0; r < 4; ++r) {
      float h[8];
      float s = 0.f;
      for (int f = 0; f < 8; ++f) { h[f] = acc[f][r] + b1r[f]; s += h[f]; }
      s += __shfl_xor(s, 1); s += __shfl_xor(s, 2);
      s += __shfl_xor(s, 4); s += __shfl_xor(s, 8);
      float mu = s * (1.f / 128.f);
      float qv = 0.f;
      for (int f = 0; f < 8; ++f) { float d0 = h[f] - mu; qv += d0 * d0; }
      qv += __shfl_xor(qv, 1); qv += __shfl_xor(qv, 2);
      qv += __shfl_xor(qv, 4); qv += __shfl_xor(qv, 8);
      float rstd = rsqrtf(qv * (1.f / 128.f) + LN_EPS);
      int row = q * 4 + r;
      for (int f = 0; f < 8; ++f) {
        float val = (h[f] - mu) * rstd * gr[f] + ber[f];
        val = fmaxf(val, 0.f);
        sPw[row * PP + f * 16 + lo] = f2bf(val);
      }
    }
    asm volatile("s_waitcnt lgkmcnt(0)" ::: "memory");  // P writes visible to own wave
    // A2 frags from P (A-layout)
    short8 a2[4];
    for (int kt = 0; kt < 4; ++kt)
      a2[kt] = *reinterpret_cast<const short8*>(&sPw[lo * PP + q * 8 + kt * 32]);
    // GEMM2: y[16x64] = P[16x128] @ W2^T ; B[k][n]=W2[n][k]
    for (int f = 0; f < 4; ++f) {
      floatx4 c = {0.f, 0.f, 0.f, 0.f};
      for (int kt = 0; kt < 4; ++kt) {
        const short8* bp = reinterpret_cast<const short8*>(
            &sW2[(f * 16 + lo) * W2P + q * 8 + kt * 32]);
        c = __builtin_amdgcn_mfma_f32_16x16x32_bf16(a2[kt], *bp, c, 0, 0, 0);
      }
      for (int r = 0; r < 4; ++r) {
        out[(size_t)(tile * 16 + q * 4 + r) * D + f * 16 + lo] = c[r] + b2r[f];
      }
    }
  }
}

extern "C" void kernel_launch(void* const* d_in, const int* in_sizes, int n_in,
                              void* d_out, int out_size, void* d_ws, size_t ws_size,
                              hipStream_t stream) {
  const float* x  = (const float*)d_in[0];
  const int* ei   = (const int*)d_in[1];
  const float* ea = (const float*)d_in[2];
  const float* W1 = (const float*)d_in[3];
  const float* b1 = (const float*)d_in[4];
  const float* g1 = (const float*)d_in[5];
  const float* be1= (const float*)d_in[6];
  const float* W2 = (const float*)d_in[7];
  const float* b2 = (const float*)d_in[8];
  float* out = (float*)d_out;

  char* ws = (char*)d_ws;
  int* cnt   = (int*)ws;                                        // 200000 B
  int* slots = (int*)(ws + 200192);                             // 12.8 MB
  float* aggout = (float*)(ws + 200192 + (size_t)N_NODES * CAP * 4);  // 12.8 MB

  hipMemsetAsync(cnt, 0, N_NODES * sizeof(int), stream);
  k_scatter<<<(N_EDGES + 255) / 256, 256, 0, stream>>>(ei, cnt, slots);
  k_agg<<<(N_NODES * 64) / 256, 256, 0, stream>>>(x, ei, ea, cnt, slots, aggout);
  k_mlp<<<196, 256, 0, stream>>>(aggout, W1, b1, g1, be1, W2, b2, out);
}

// Round 4
// 408.452 us; speedup vs baseline: 1.2304x; 1.2304x over previous
//
#include <hip/hip_runtime.h>
#include <cstdint>
#include <cstddef>

#define N_NODES 50000
#define N_EDGES 800000
#define D 64
#define CAP 64
#define MSG_EPS 1e-7f
#define LN_EPS 1e-5f

typedef __attribute__((ext_vector_type(8))) short short8;
typedef __attribute__((ext_vector_type(4))) float floatx4;

__device__ __forceinline__ unsigned short f2bf(float f) {
  unsigned u = __float_as_uint(f);
  u += 0x7FFFu + ((u >> 16) & 1u);
  return (unsigned short)(u >> 16);
}

// ---------------- K1: bucket edges by dst ----------------
__global__ __launch_bounds__(256) void k_scatter(const int* __restrict__ ei,
                                                 int* __restrict__ cnt,
                                                 int* __restrict__ slots) {
  int e = blockIdx.x * blockDim.x + threadIdx.x;
  if (e < N_EDGES) {
    int d = ei[N_EDGES + e];  // dst row of edge_index
    int pos = atomicAdd(&cnt[d], 1);
    if (pos < CAP) slots[d * CAP + pos] = e;
  }
}

// ---------------- K2: per-node online-softmax aggregation ----------------
// R1 addressing (per-iteration slot/ei loads, NO preload/shfl), R1 math and
// update order. ONLY change: manual 4x unroll with loads hoisted so 4
// independent slot->ei->row chains are in flight per iteration.
__global__ __launch_bounds__(256) void k_agg(const float* __restrict__ x,
                                             const int* __restrict__ ei,
                                             const float* __restrict__ ea,
                                             const int* __restrict__ cnt,
                                             const int* __restrict__ slots,
                                             float* __restrict__ aggout) {
  int w = (blockIdx.x * blockDim.x + threadIdx.x) >> 6;  // node id
  int l = threadIdx.x & 63;                              // channel
  if (w >= N_NODES) return;
  int deg = cnt[w];
  deg = deg > CAP ? CAP : deg;
  const int* sl = slots + w * CAP;
  float m = 0.f, dsum = 0.f, nsum = 0.f;  // msg >= eps > 0, so m=0 init is safe
  int k = 0;
  for (; k + 3 < deg; k += 4) {
    int e0 = sl[k], e1 = sl[k + 1], e2 = sl[k + 2], e3 = sl[k + 3];
    int s0 = ei[e0], s1 = ei[e1], s2 = ei[e2], s3 = ei[e3];
    float a0 = ea[(size_t)e0 * D + l];
    float a1 = ea[(size_t)e1 * D + l];
    float a2 = ea[(size_t)e2 * D + l];
    float a3 = ea[(size_t)e3 * D + l];
    float x0 = x[(size_t)s0 * D + l];
    float x1 = x[(size_t)s1 * D + l];
    float x2 = x[(size_t)s2 * D + l];
    float x3 = x[(size_t)s3 * D + l];
    {
      float v = fmaxf(a0 + x0, 0.f) + MSG_EPS;
      float nm = fmaxf(m, v);
      float sc = __expf(m - nm);
      float ev = __expf(v - nm);
      dsum = dsum * sc + ev;
      nsum = nsum * sc + ev * v;
      m = nm;
    }
    {
      float v = fmaxf(a1 + x1, 0.f) + MSG_EPS;
      float nm = fmaxf(m, v);
      float sc = __expf(m - nm);
      float ev = __expf(v - nm);
      dsum = dsum * sc + ev;
      nsum = nsum * sc + ev * v;
      m = nm;
    }
    {
      float v = fmaxf(a2 + x2, 0.f) + MSG_EPS;
      float nm = fmaxf(m, v);
      float sc = __expf(m - nm);
      float ev = __expf(v - nm);
      dsum = dsum * sc + ev;
      nsum = nsum * sc + ev * v;
      m = nm;
    }
    {
      float v = fmaxf(a3 + x3, 0.f) + MSG_EPS;
      float nm = fmaxf(m, v);
      float sc = __expf(m - nm);
      float ev = __expf(v - nm);
      dsum = dsum * sc + ev;
      nsum = nsum * sc + ev * v;
      m = nm;
    }
  }
  for (; k < deg; ++k) {
    int e = sl[k];
    int s = ei[e];
    float v = ea[(size_t)e * D + l] + x[(size_t)s * D + l];
    v = fmaxf(v, 0.f) + MSG_EPS;
    float nm = fmaxf(m, v);
    float sc = __expf(m - nm);
    float ev = __expf(v - nm);
    dsum = dsum * sc + ev;
    nsum = nsum * sc + ev * v;
    m = nm;
  }
  float agg = (deg > 0) ? (nsum / dsum) : 0.f;
  aggout[(size_t)w * D + l] = agg + x[(size_t)w * D + l];
}

// ---------------- K3: fused MLP (GEMM1 + LN + ReLU + GEMM2), bf16 MFMA ----------------
#define W1P 72    // 64 + 8 pad (bf16 elems)
#define W2P 136   // 128 + 8 pad
#define PP 136

__global__ __launch_bounds__(256) void k_mlp(const float* __restrict__ o,
                                             const float* __restrict__ W1,
                                             const float* __restrict__ b1,
                                             const float* __restrict__ g1,
                                             const float* __restrict__ be1,
                                             const float* __restrict__ W2,
                                             const float* __restrict__ b2,
                                             float* __restrict__ out) {
  __shared__ unsigned short sW1[128 * W1P];
  __shared__ unsigned short sW2[64 * W2P];
  __shared__ unsigned short sP[4][16 * PP];
  int t = threadIdx.x;
  for (int i = t; i < 128 * 64; i += 256) {
    int n = i >> 6, k = i & 63;
    sW1[n * W1P + k] = f2bf(W1[i]);
  }
  for (int i = t; i < 64 * 128; i += 256) {
    int n = i >> 7, k = i & 127;
    sW2[n * W2P + k] = f2bf(W2[i]);
  }
  __syncthreads();

  int w = t >> 6, l = t & 63;
  int lo = l & 15, q = l >> 4;
  unsigned short* sPw = sP[w];

  float b1r[8], gr[8], ber[8];
  for (int f = 0; f < 8; ++f) {
    b1r[f] = b1[f * 16 + lo];
    gr[f]  = g1[f * 16 + lo];
    ber[f] = be1[f * 16 + lo];
  }
  float b2r[4];
  for (int f = 0; f < 4; ++f) b2r[f] = b2[f * 16 + lo];

  const int n_waves = 196 * 4;
  int wave_global = blockIdx.x * 4 + w;
  for (int tile = wave_global; tile < N_NODES / 16; tile += n_waves) {
    short8 a1[2];
    const float* arow = o + (size_t)(tile * 16 + lo) * D + q * 8;
    for (int kt = 0; kt < 2; ++kt) {
      const float4* p = reinterpret_cast<const float4*>(arow + kt * 32);
      float4 u = p[0], v2 = p[1];
      short8 r;
      r[0] = f2bf(u.x);  r[1] = f2bf(u.y);  r[2] = f2bf(u.z);  r[3] = f2bf(u.w);
      r[4] = f2bf(v2.x); r[5] = f2bf(v2.y); r[6] = f2bf(v2.z); r[7] = f2bf(v2.w);
      a1[kt] = r;
    }
    floatx4 acc[8];
    for (int f = 0; f < 8; ++f) {
      floatx4 c = {0.f, 0.f, 0.f, 0.f};
      for (int kt = 0; kt < 2; ++kt) {
        const short8* bp = reinterpret_cast<const short8*>(
            &sW1[(f * 16 + lo) * W1P + q * 8 + kt * 32]);
        c = __builtin_amdgcn_mfma_f32_16x16x32_bf16(a1[kt], *bp, c, 0, 0, 0);
      }
      acc[f] = c;
    }
    asm volatile("s_waitcnt lgkmcnt(0)" ::: "memory");
    for (int r = 0; r < 4; ++r) {
      float h[8];
      float s = 0.f;
      for (int f = 0; f < 8; ++f) { h[f] = acc[f][r] + b1r[f]; s += h[f]; }
      s += __shfl_xor(s, 1); s += __shfl_xor(s, 2);
      s += __shfl_xor(s, 4); s += __shfl_xor(s, 8);
      float mu = s * (1.f / 128.f);
      float qv = 0.f;
      for (int f = 0; f < 8; ++f) { float d0 = h[f] - mu; qv += d0 * d0; }
      qv += __shfl_xor(qv, 1); qv += __shfl_xor(qv, 2);
      qv += __shfl_xor(qv, 4); qv += __shfl_xor(qv, 8);
      float rstd = rsqrtf(qv * (1.f / 128.f) + LN_EPS);
      int row = q * 4 + r;
      for (int f = 0; f < 8; ++f) {
        float val = (h[f] - mu) * rstd * gr[f] + ber[f];
        val = fmaxf(val, 0.f);
        sPw[row * PP + f * 16 + lo] = f2bf(val);
      }
    }
    asm volatile("s_waitcnt lgkmcnt(0)" ::: "memory");
    short8 a2[4];
    for (int kt = 0; kt < 4; ++kt)
      a2[kt] = *reinterpret_cast<const short8*>(&sPw[lo * PP + q * 8 + kt * 32]);
    for (int f = 0; f < 4; ++f) {
      floatx4 c = {0.f, 0.f, 0.f, 0.f};
      for (int kt = 0; kt < 4; ++kt) {
        const short8* bp = reinterpret_cast<const short8*>(
            &sW2[(f * 16 + lo) * W2P + q * 8 + kt * 32]);
        c = __builtin_amdgcn_mfma_f32_16x16x32_bf16(a2[kt], *bp, c, 0, 0, 0);
      }
      for (int r = 0; r < 4; ++r) {
        out[(size_t)(tile * 16 + q * 4 + r) * D + f * 16 + lo] = c[r] + b2r[f];
      }
    }
  }
}

extern "C" void kernel_launch(void* const* d_in, const int* in_sizes, int n_in,
                              void* d_out, int out_size, void* d_ws, size_t ws_size,
                              hipStream_t stream) {
  const float* x  = (const float*)d_in[0];
  const int* ei   = (const int*)d_in[1];
  const float* ea = (const float*)d_in[2];
  const float* W1 = (const float*)d_in[3];
  const float* b1 = (const float*)d_in[4];
  const float* g1 = (const float*)d_in[5];
  const float* be1= (const float*)d_in[6];
  const float* W2 = (const float*)d_in[7];
  const float* b2 = (const float*)d_in[8];
  float* out = (float*)d_out;

  char* ws = (char*)d_ws;
  int* cnt   = (int*)ws;                                              // 200 KB
  int* slots = (int*)(ws + 200192);                                   // 12.8 MB
  float* aggout = (float*)(ws + 200192 + (size_t)N_NODES * CAP * 4);  // 12.8 MB

  hipMemsetAsync(cnt, 0, N_NODES * sizeof(int), stream);
  k_scatter<<<(N_EDGES + 255) / 256, 256, 0, stream>>>(ei, cnt, slots);
  k_agg<<<(N_NODES * 64) / 256, 256, 0, stream>>>(x, ei, ea, cnt, slots, aggout);
  k_mlp<<<196, 256, 0, stream>>>(aggout, W1, b1, g1, be1, W2, b2, out);
}